// Round 2
// baseline (285.611 us; speedup 1.0000x reference)
//
#include <hip/hip_runtime.h>
#include <hip/hip_bf16.h>
#include <cstdint>

#define N_ROWS 8192
#define DIM    1024

typedef __attribute__((ext_vector_type(4))) float  f32x4;
typedef __attribute__((ext_vector_type(8))) __bf16 bf16x8;

__device__ __forceinline__ unsigned short f2bf(float x) {
    unsigned int u = __float_as_uint(x);
    u += 0x7fffu + ((u >> 16) & 1u);   // round-to-nearest-even
    return (unsigned short)(u >> 16);
}

// ---------------------------------------------------------------------------
// Kernel 1: per-row L2 normalize (fp32 -> bf16), fp32 diagonal logit, zero S.
// ---------------------------------------------------------------------------
__global__ __launch_bounds__(256) void normalize_kernel(
    const float* __restrict__ A, const float* __restrict__ B,
    short* __restrict__ Abf, short* __restrict__ Bbf,
    float* __restrict__ diag, float* __restrict__ S)
{
    const int row  = blockIdx.x;
    const int t    = threadIdx.x;
    const int lane = t & 63;
    const int wave = t >> 6;

    const float4 a = reinterpret_cast<const float4*>(A)[row * (DIM / 4) + t];
    const float4 b = reinterpret_cast<const float4*>(B)[row * (DIM / 4) + t];

    float ssA = a.x * a.x + a.y * a.y + a.z * a.z + a.w * a.w;
    float ssB = b.x * b.x + b.y * b.y + b.z * b.z + b.w * b.w;
#pragma unroll
    for (int m = 1; m < 64; m <<= 1) {
        ssA += __shfl_xor(ssA, m);
        ssB += __shfl_xor(ssB, m);
    }
    __shared__ float redA[4], redB[4];
    if (lane == 0) { redA[wave] = ssA; redB[wave] = ssB; }
    __syncthreads();
    ssA = redA[0] + redA[1] + redA[2] + redA[3];
    ssB = redB[0] + redB[1] + redB[2] + redB[3];

    const float ia = 1.0f / fmaxf(sqrtf(ssA), 1e-8f);
    const float ib = 1.0f / fmaxf(sqrtf(ssB), 1e-8f);

    const float anx = a.x * ia, any = a.y * ia, anz = a.z * ia, anw = a.w * ia;
    const float bnx = b.x * ib, bny = b.y * ib, bnz = b.z * ib, bnw = b.w * ib;

    ushort4 pa, pb;
    pa.x = f2bf(anx); pa.y = f2bf(any); pa.z = f2bf(anz); pa.w = f2bf(anw);
    pb.x = f2bf(bnx); pb.y = f2bf(bny); pb.z = f2bf(bnz); pb.w = f2bf(bnw);
    reinterpret_cast<ushort4*>(Abf)[row * (DIM / 4) + t] = pa;
    reinterpret_cast<ushort4*>(Bbf)[row * (DIM / 4) + t] = pb;

    float d = anx * bnx + any * bny + anz * bnz + anw * bnw;
#pragma unroll
    for (int m = 1; m < 64; m <<= 1) d += __shfl_xor(d, m);
    __shared__ float redD[4];
    if (lane == 0) redD[wave] = d;
    __syncthreads();
    if (t == 0) {
        diag[row] = (redD[0] + redD[1] + redD[2] + redD[3]) * 10.0f;  // /T
        S[row] = 0.0f;   // ws is poisoned 0xAA each launch
    }
}

// ---------------------------------------------------------------------------
// Kernel 2: 256x256x(BK=64) 8-phase bf16 GEMM (A·B^T) fused with
// exp(logit-10) row-sum epilogue.  Structure = m201 template:
//   8 waves (2M x 4N), per-wave 128x64 C, acc f32x4[8][4]
//   LDS 128 KiB = 2 K-tile dbuf x (A[256][64] + B[256][64]) bf16
//   XOR swizzle (byte^=bits9,10 -> bits5,6) applied to BOTH the
//   global_load_lds source and the ds_read address (involution, rule #21)
//   per K-tile: 4 phases, quadrants (0,0)(0,1)(1,1)(1,0), ds_reads 12/4/8/4
//   1 half-tile (2 global_load_lds/thread) staged per phase
//   vmcnt(6) at phases 4/8 only (3 half-tiles in flight), raw s_barrier,
//   setprio(1) around each 16-MFMA cluster.
// Stage schedule (verified region lifetimes):
//   even ph1: (kt+1).B0->buf1 | ph2: (kt+2).A0->buf0 | ph3: (kt+2).B1 | ph4: (kt+2).A1
//   odd  ph5: (kt+2).B0->buf0 | ph6: (kt+3).A0->buf1 | ph7: (kt+3).B1 | ph8: (kt+3).A1
// Each region is staged strictly after its last read (barrier between), and
// every read is covered by the preceding vmcnt(6) drain.
// ---------------------------------------------------------------------------
#define BAR()   __builtin_amdgcn_s_barrier()
#define LGKM0() asm volatile("s_waitcnt lgkmcnt(0)" ::: "memory")
#define LGKM8() asm volatile("s_waitcnt lgkmcnt(8)" ::: "memory")
#define VM6()   asm volatile("s_waitcnt vmcnt(6)" ::: "memory")
#define VM0()   asm volatile("s_waitcnt vmcnt(0)" ::: "memory")

// stage one 128x64 bf16 half-tile: 512 thr x 2 x 16B, linear LDS dest,
// inverse-swizzled global source.
__device__ __forceinline__ void stage_half(const short* __restrict__ gsrc,
                                           short* ldst, int t)
{
#pragma unroll
    for (int i = 0; i < 2; i++) {
        const int d    = (i * 512 + t) * 16;              // dest byte 0..16383
        const int row  = d >> 7;                          // 0..127
        const int colb = (d & 127) ^ ((d >> 4) & 96);     // swz: bits9,10 -> 5,6
        __builtin_amdgcn_global_load_lds(
            (const __attribute__((address_space(1))) void*)((const char*)gsrc + (size_t)row * (DIM * 2) + colb),
            (__attribute__((address_space(3))) void*)((char*)ldst + d), 16, 0, 0);
    }
}

template<int MH>
__device__ __forceinline__ void lda_f(const char* base, int wr, int lm, int lk,
                                      bf16x8 (&aF)[4][2])
{
#pragma unroll
    for (int m = 0; m < 4; m++)
#pragma unroll
        for (int ks = 0; ks < 2; ks++) {
            const int row = wr * 128 + MH * 64 + m * 16 + lm;
            const int b   = (row * 128 + ks * 64 + lk * 16) ^ ((row & 12) << 3);
            aF[m][ks] = *reinterpret_cast<const bf16x8*>(base + b);
        }
}

template<int NH>
__device__ __forceinline__ void ldb_f(const char* base, int wc, int lm, int lk,
                                      bf16x8 (&bF)[2][2])
{
#pragma unroll
    for (int n = 0; n < 2; n++)
#pragma unroll
        for (int ks = 0; ks < 2; ks++) {
            const int row = wc * 64 + NH * 32 + n * 16 + lm;
            const int b   = (row * 128 + ks * 64 + lk * 16) ^ ((row & 12) << 3);
            bF[n][ks] = *reinterpret_cast<const bf16x8*>(base + b);
        }
}

template<int MH, int NH>
__device__ __forceinline__ void mma16(const bf16x8 (&aF)[4][2],
                                      const bf16x8 (&bF)[2][2],
                                      f32x4 (&acc)[8][4])
{
    __builtin_amdgcn_s_setprio(1);
#pragma unroll
    for (int m = 0; m < 4; m++)
#pragma unroll
        for (int n = 0; n < 2; n++)
#pragma unroll
            for (int ks = 0; ks < 2; ks++)
                acc[MH * 4 + m][NH * 2 + n] = __builtin_amdgcn_mfma_f32_16x16x32_bf16(
                    aF[m][ks], bF[n][ks], acc[MH * 4 + m][NH * 2 + n], 0, 0, 0);
    __builtin_amdgcn_s_setprio(0);
}

__global__ __launch_bounds__(512, 2) void gemm_lse_kernel(
    const short* __restrict__ Abf, const short* __restrict__ Bbf,
    float* __restrict__ S)
{
    extern __shared__ short lds[];   // 131072 B: A[2][256][64] | B[2][256][64]

    const int t    = threadIdx.x;    // 0..511
    const int lane = t & 63;
    const int wave = t >> 6;         // 0..7
    const int wr   = wave >> 2;      // 0..1  (M halves of 256)
    const int wc   = wave & 3;       // 0..3  (N quarters of 256)
    const int lm   = lane & 15;
    const int lk   = lane >> 4;

    // XCD-aware bijective swizzle (nwg=1024, divisible by 8)
    const int bid   = (blockIdx.x & 7) * 128 + (blockIdx.x >> 3);
    const int tileM = bid >> 5;      // 0..31
    const int tileN = bid & 31;      // 0..31

    const short* Ag = Abf + (size_t)tileM * 256 * DIM;
    const short* Bg = Bbf + (size_t)tileN * 256 * DIM;

    char* const A0 = (char*)(lds);            // A buf0 [256][64]
    char* const A1 = (char*)(lds + 16384);    // A buf1
    char* const B0 = (char*)(lds + 32768);    // B buf0
    char* const B1 = (char*)(lds + 49152);    // B buf1

#define SA(buf, h, kt) stage_half(Ag + (h) * 128 * DIM + (kt) * 64, lds + (buf) * 16384 + (h) * 8192, t)
#define SB(buf, h, kt) stage_half(Bg + (h) * 128 * DIM + (kt) * 64, lds + 32768 + (buf) * 16384 + (h) * 8192, t)

    // ---- prologue: k-tile 0 complete + k-tile 1 {A0,B1,A1}; 3 half-tiles in flight
    SA(0, 0, 0); SB(0, 1, 0); SA(0, 1, 0); SB(0, 0, 0);
    SA(1, 0, 1); SB(1, 1, 1); SA(1, 1, 1);
    VM6();
    BAR();

    f32x4 acc[8][4];
#pragma unroll
    for (int m = 0; m < 8; m++)
#pragma unroll
        for (int n = 0; n < 4; n++) acc[m][n] = (f32x4){0.f, 0.f, 0.f, 0.f};

    bf16x8 aF[4][2], bF[2][2];

    for (int it = 0; it < 8; ++it) {
        const int kt = 2 * it;
        const bool s2 = (it < 7);    // stage k-tiles kt+2 / kt+3 ?

        // ================= even block: compute k-tile kt from buf0 ===========
        // ph1 : quadrant (0,0)
        lda_f<0>(A0, wr, lm, lk, aF);
        ldb_f<0>(B0, wc, lm, lk, bF);
        SB(1, 0, kt + 1);
        LGKM8();
        BAR(); LGKM0();
        mma16<0, 0>(aF, bF, acc);
        BAR();
        // ph2 : quadrant (0,1)
        ldb_f<1>(B0, wc, lm, lk, bF);
        if (s2) SA(0, 0, kt + 2);
        BAR(); LGKM0();
        mma16<0, 1>(aF, bF, acc);
        BAR();
        // ph3 : quadrant (1,1)
        lda_f<1>(A0, wr, lm, lk, aF);
        if (s2) SB(0, 1, kt + 2);
        BAR(); LGKM0();
        mma16<1, 1>(aF, bF, acc);
        BAR();
        // ph4 : quadrant (1,0)
        ldb_f<0>(B0, wc, lm, lk, bF);
        if (s2) SA(0, 1, kt + 2);
        BAR(); LGKM0();
        mma16<1, 0>(aF, bF, acc);
        if (s2) { VM6(); } else { VM0(); }
        BAR();

        // ================= odd block: compute k-tile kt+1 from buf1 ==========
        // ph5 : quadrant (0,0)
        lda_f<0>(A1, wr, lm, lk, aF);
        ldb_f<0>(B1, wc, lm, lk, bF);
        if (s2) SB(0, 0, kt + 2);
        LGKM8();
        BAR(); LGKM0();
        mma16<0, 0>(aF, bF, acc);
        BAR();
        // ph6 : quadrant (0,1)
        ldb_f<1>(B1, wc, lm, lk, bF);
        if (s2) SA(1, 0, kt + 3);
        BAR(); LGKM0();
        mma16<0, 1>(aF, bF, acc);
        BAR();
        // ph7 : quadrant (1,1)
        lda_f<1>(A1, wr, lm, lk, aF);
        if (s2) SB(1, 1, kt + 3);
        BAR(); LGKM0();
        mma16<1, 1>(aF, bF, acc);
        BAR();
        // ph8 : quadrant (1,0)
        ldb_f<0>(B1, wc, lm, lk, bF);
        if (s2) SA(1, 1, kt + 3);
        BAR(); LGKM0();
        mma16<1, 0>(aF, bF, acc);
        if (s2) { VM6(); }
        BAR();
    }
#undef SA
#undef SB

    // ---- epilogue: exp2(acc*C1 - C1), 16-lane row reduce, atomicAdd ----
    // C/D layout: col = lane&15, row = (lane>>4)*4 + reg  [m89/m91]
    float* rowpart = (float*)lds;    // [256][4] f32 (4 KB, buf0-A region, dead)
    constexpr float C1 = 14.4269504088896340736f;   // 10 * log2(e)

#pragma unroll
    for (int mi = 0; mi < 8; mi++) {
#pragma unroll
        for (int r = 0; r < 4; r++) {
            float s = 0.f;
#pragma unroll
            for (int n = 0; n < 4; n++)
                s += exp2f(fmaf(acc[mi][n][r], C1, -C1));
#pragma unroll
            for (int msk = 1; msk < 16; msk <<= 1) s += __shfl_xor(s, msk);
            if (lm == 0)
                rowpart[(wr * 128 + mi * 16 + lk * 4 + r) * 4 + wc] = s;
        }
    }
    __syncthreads();
    if (t < 256) {
        const float v = rowpart[t * 4 + 0] + rowpart[t * 4 + 1] +
                        rowpart[t * 4 + 2] + rowpart[t * 4 + 3];
        atomicAdd(&S[tileM * 256 + t], v);
    }
}

// ---------------------------------------------------------------------------
// Kernel 3: loss = mean_i( 10 + log(S_i) - diag_i )
// ---------------------------------------------------------------------------
__global__ __launch_bounds__(1024) void loss_kernel(
    const float* __restrict__ S, const float* __restrict__ diag,
    float* __restrict__ out)
{
    const int t = threadIdx.x;
    float acc = 0.f;
    for (int i = t; i < N_ROWS; i += 1024)
        acc += 10.0f + logf(S[i]) - diag[i];
#pragma unroll
    for (int m = 1; m < 64; m <<= 1) acc += __shfl_xor(acc, m);
    __shared__ float red[16];
    if ((t & 63) == 0) red[t >> 6] = acc;
    __syncthreads();
    if (t == 0) {
        float s = 0.f;
        for (int i = 0; i < 16; i++) s += red[i];
        out[0] = s * (1.0f / N_ROWS);
    }
}

// ---------------------------------------------------------------------------
extern "C" void kernel_launch(void* const* d_in, const int* in_sizes, int n_in,
                              void* d_out, int out_size, void* d_ws, size_t ws_size,
                              hipStream_t stream)
{
    const float* A = (const float*)d_in[0];   // image_emb  [8192,1024] f32
    const float* B = (const float*)d_in[1];   // sensor_emb [8192,1024] f32
    float* out = (float*)d_out;

    short* a_bf = (short*)d_ws;
    short* b_bf = a_bf + (size_t)N_ROWS * DIM;
    float* S    = (float*)(b_bf + (size_t)N_ROWS * DIM);
    float* diag = S + N_ROWS;

    normalize_kernel<<<N_ROWS, 256, 0, stream>>>(A, B, a_bf, b_bf, diag, S);
    gemm_lse_kernel<<<1024, 512, 131072, stream>>>(a_bf, b_bf, S);
    loss_kernel<<<1, 1024, 0, stream>>>(S, diag, out);
}

// Round 4
// 270.064 us; speedup vs baseline: 1.0576x; 1.0576x over previous
//
#include <hip/hip_runtime.h>
#include <hip/hip_bf16.h>
#include <cstdint>

#define N_ROWS 8192
#define DIM    1024

typedef __attribute__((ext_vector_type(4))) float  f32x4;
typedef __attribute__((ext_vector_type(8))) __bf16 bf16x8;

__device__ __forceinline__ unsigned short f2bf(float x) {
    unsigned int u = __float_as_uint(x);
    u += 0x7fffu + ((u >> 16) & 1u);   // round-to-nearest-even
    return (unsigned short)(u >> 16);
}

// ---------------------------------------------------------------------------
// Kernel 1: per-row L2 normalize (fp32 -> bf16), fp32 diagonal logit, zero S.
// ---------------------------------------------------------------------------
__global__ __launch_bounds__(256) void normalize_kernel(
    const float* __restrict__ A, const float* __restrict__ B,
    short* __restrict__ Abf, short* __restrict__ Bbf,
    float* __restrict__ diag, float* __restrict__ S)
{
    const int row  = blockIdx.x;
    const int t    = threadIdx.x;
    const int lane = t & 63;
    const int wave = t >> 6;

    const float4 a = reinterpret_cast<const float4*>(A)[row * (DIM / 4) + t];
    const float4 b = reinterpret_cast<const float4*>(B)[row * (DIM / 4) + t];

    float ssA = a.x * a.x + a.y * a.y + a.z * a.z + a.w * a.w;
    float ssB = b.x * b.x + b.y * b.y + b.z * b.z + b.w * b.w;
#pragma unroll
    for (int m = 1; m < 64; m <<= 1) {
        ssA += __shfl_xor(ssA, m);
        ssB += __shfl_xor(ssB, m);
    }
    __shared__ float redA[4], redB[4];
    if (lane == 0) { redA[wave] = ssA; redB[wave] = ssB; }
    __syncthreads();
    ssA = redA[0] + redA[1] + redA[2] + redA[3];
    ssB = redB[0] + redB[1] + redB[2] + redB[3];

    const float ia = 1.0f / fmaxf(sqrtf(ssA), 1e-8f);
    const float ib = 1.0f / fmaxf(sqrtf(ssB), 1e-8f);

    const float anx = a.x * ia, any = a.y * ia, anz = a.z * ia, anw = a.w * ia;
    const float bnx = b.x * ib, bny = b.y * ib, bnz = b.z * ib, bnw = b.w * ib;

    ushort4 pa, pb;
    pa.x = f2bf(anx); pa.y = f2bf(any); pa.z = f2bf(anz); pa.w = f2bf(anw);
    pb.x = f2bf(bnx); pb.y = f2bf(bny); pb.z = f2bf(bnz); pb.w = f2bf(bnw);
    reinterpret_cast<ushort4*>(Abf)[row * (DIM / 4) + t] = pa;
    reinterpret_cast<ushort4*>(Bbf)[row * (DIM / 4) + t] = pb;

    float d = anx * bnx + any * bny + anz * bnz + anw * bnw;
#pragma unroll
    for (int m = 1; m < 64; m <<= 1) d += __shfl_xor(d, m);
    __shared__ float redD[4];
    if (lane == 0) redD[wave] = d;
    __syncthreads();
    if (t == 0) {
        diag[row] = (redD[0] + redD[1] + redD[2] + redD[3]) * 10.0f;  // /T
        S[row] = 0.0f;   // ws is poisoned 0xAA each launch
    }
}

// ---------------------------------------------------------------------------
// Kernel 2: 256x256x(BK=64) 8-phase bf16 GEMM (A·B^T) + exp(logit-10) row-sum.
// m201-family template, round-3 fixes:
//  * LDS swizzle = byte ^ ((row&7)<<4)  (row bits0-2 -> addr bits4-6 = the
//    bank-group bits of a b128 chunk; conflict-free read pattern), applied to
//    BOTH global_load_lds source and ds_read address (involution, rule #21).
//  * Race-free stage schedule from true region lifetimes:
//      reads per K-tile (quadrants (0,0)(0,1)(1,1)(1,0)):
//        A0: ph1,ph3   B0: ph1,ph4   A1: ph5,ph7   B1: ph5,ph8
//      stages (full tile = 4 loads/thread):
//        ph1: B1<-kt+1 | ph4: A0<-kt+2 | ph5: B0<-kt+2 | ph8: A1<-kt+3
//      every staged tile lands >=3 phases before its first read.
//  * vmcnt(4) at end-ph4 / end-ph8 (tail iter: vmcnt(0) at ph4, none at ph8).
//  * XCD mapping: seq bits -> (colgrp, mLoc, nLoc): 32 concurrent blocks per
//    XCD cover 4 tileM x 8 tileN (6 MB working set vs 16.5 MB before).
// ---------------------------------------------------------------------------
#define BAR()   __builtin_amdgcn_s_barrier()
#define LGKM0() asm volatile("s_waitcnt lgkmcnt(0)" ::: "memory")
#define LGKM8() asm volatile("s_waitcnt lgkmcnt(8)" ::: "memory")
#define VM4()   asm volatile("s_waitcnt vmcnt(4)" ::: "memory")
#define VM0()   asm volatile("s_waitcnt vmcnt(0)" ::: "memory")

// stage one 128x64 bf16 half-tile: 512 thr x 2 x 16B, linear LDS dest,
// inverse-swizzled global source (XOR is row-constant per 8-lane row group
// -> each row is still one contiguous 128B segment).
__device__ __forceinline__ void stage_half(const short* __restrict__ gsrc,
                                           short* ldst, int t)
{
#pragma unroll
    for (int i = 0; i < 2; i++) {
        const int d    = (i * 512 + t) * 16;                 // dest byte 0..16383
        const int row  = d >> 7;                             // 0..127
        const int colb = (d & 127) ^ ((row & 7) << 4);       // swz bits4-6
        __builtin_amdgcn_global_load_lds(
            (const __attribute__((address_space(1))) void*)((const char*)gsrc + (size_t)row * (DIM * 2) + colb),
            (__attribute__((address_space(3))) void*)((char*)ldst + d), 16, 0, 0);
    }
}

template<int MH>
__device__ __forceinline__ void lda_f(const char* base, int wr, int lm, int lk,
                                      bf16x8 (&aF)[4][2])
{
#pragma unroll
    for (int m = 0; m < 4; m++)
#pragma unroll
        for (int ks = 0; ks < 2; ks++) {
            const int row = wr * 128 + MH * 64 + m * 16 + lm;
            const int b   = (row * 128 + ks * 64 + lk * 16) ^ ((row & 7) << 4);
            aF[m][ks] = *reinterpret_cast<const bf16x8*>(base + b);
        }
}

template<int NH>
__device__ __forceinline__ void ldb_f(const char* base, int wc, int lm, int lk,
                                      bf16x8 (&bF)[2][2])
{
#pragma unroll
    for (int n = 0; n < 2; n++)
#pragma unroll
        for (int ks = 0; ks < 2; ks++) {
            const int row = wc * 64 + NH * 32 + n * 16 + lm;
            const int b   = (row * 128 + ks * 64 + lk * 16) ^ ((row & 7) << 4);
            bF[n][ks] = *reinterpret_cast<const bf16x8*>(base + b);
        }
}

template<int MH, int NP>
__device__ __forceinline__ void mma16(const bf16x8 (&aF)[4][2],
                                      const bf16x8 (&bF)[2][2],
                                      f32x4 (&acc)[8][4])
{
    __builtin_amdgcn_s_setprio(1);
#pragma unroll
    for (int m = 0; m < 4; m++)
#pragma unroll
        for (int n = 0; n < 2; n++)
#pragma unroll
            for (int ks = 0; ks < 2; ks++)
                acc[MH * 4 + m][NP * 2 + n] = __builtin_amdgcn_mfma_f32_16x16x32_bf16(
                    aF[m][ks], bF[n][ks], acc[MH * 4 + m][NP * 2 + n], 0, 0, 0);
    __builtin_amdgcn_s_setprio(0);
}

__global__ __launch_bounds__(512, 2) void gemm_lse_kernel(
    const short* __restrict__ Abf, const short* __restrict__ Bbf,
    float* __restrict__ S)
{
    extern __shared__ short lds[];   // 131072 B: A0|A1|B0|B1, each [256][64] bf16

    const int t    = threadIdx.x;    // 0..511
    const int lane = t & 63;
    const int wave = t >> 6;         // 0..7
    const int wr   = wave >> 2;      // 0..1  (M halves of 256)
    const int wc   = wave & 3;       // 0..3  (N quarters of 256)
    const int lm   = lane & 15;
    const int lk   = lane >> 4;

    // XCD mapping: xcd = b&7, seq bits [6:4]=colgrp, [3:2]=mLoc, [1:0]=nLoc.
    // Concurrent 32 blocks/XCD = 4 tileM x 8 tileN (A 2MB + B 4MB working set).
    const int xcd  = blockIdx.x & 7;
    const int seq  = blockIdx.x >> 3;          // 0..127
    const int tileM = xcd * 4 + ((seq >> 2) & 3);
    const int tileN = (seq >> 4) * 4 + (seq & 3);

    const short* Ag = Abf + (size_t)tileM * 256 * DIM;
    const short* Bg = Bbf + (size_t)tileN * 256 * DIM;

    char* const A0 = (char*)lds;               // [256][64] bf16 = 32 KiB
    char* const A1 = (char*)lds + 32768;
    char* const B0 = (char*)lds + 65536;
    char* const B1 = (char*)lds + 98304;

    // full-tile stage = both halves = 4 loads/thread
#define SA(buf, kt) { stage_half(Ag + (size_t)0 * 128 * DIM + (kt) * 64, lds + (buf) * 16384 + 0 * 8192, t); \
                      stage_half(Ag + (size_t)1 * 128 * DIM + (kt) * 64, lds + (buf) * 16384 + 1 * 8192, t); }
#define SB(buf, kt) { stage_half(Bg + (size_t)0 * 128 * DIM + (kt) * 64, lds + 32768 + (buf) * 16384 + 0 * 8192, t); \
                      stage_half(Bg + (size_t)1 * 128 * DIM + (kt) * 64, lds + 32768 + (buf) * 16384 + 1 * 8192, t); }

    // ---- prologue: A0,B0 <- kt0 (8 loads), A1 <- kt1 (4 loads); drain kt0.
    SA(0, 0); SB(0, 0);
    SA(1, 1);
    VM4();        // kt0 complete; A1(kt1) still in flight
    BAR();

    f32x4 acc[8][4];
#pragma unroll
    for (int m = 0; m < 8; m++)
#pragma unroll
        for (int n = 0; n < 4; n++) acc[m][n] = (f32x4){0.f, 0.f, 0.f, 0.f};

    bf16x8 aF[4][2], bF[2][2];

    for (int it = 0; it < 8; ++it) {
        const int kt = 2 * it;
        const bool s2 = (it < 7);

        // ===== even block: k-tile kt from buf0 =====
        // ph1 : (0,0)  reads A0<0>, B0<0>; stage B1 <- kt+1 (always needed)
        lda_f<0>(A0, wr, lm, lk, aF);
        ldb_f<0>(B0, wc, lm, lk, bF);
        SB(1, kt + 1);
        LGKM8();
        BAR(); LGKM0();
        mma16<0, 0>(aF, bF, acc);
        BAR();
        // ph2 : (0,1)  reads B0<1>
        ldb_f<1>(B0, wc, lm, lk, bF);
        BAR(); LGKM0();
        mma16<0, 1>(aF, bF, acc);
        BAR();
        // ph3 : (1,1)  reads A0<1>  (A0 free after this phase)
        lda_f<1>(A0, wr, lm, lk, aF);
        BAR(); LGKM0();
        mma16<1, 1>(aF, bF, acc);
        BAR();
        // ph4 : (1,0)  re-reads B0<0> (B0 free after); stage A0 <- kt+2
        ldb_f<0>(B0, wc, lm, lk, bF);
        if (s2) SA(0, kt + 2);
        BAR(); LGKM0();
        mma16<1, 0>(aF, bF, acc);
        if (s2) { VM4(); } else { VM0(); }   // A1,B1 (kt+1) complete before ph5
        BAR();

        // ===== odd block: k-tile kt+1 from buf1 =====
        // ph5 : (0,0)  reads A1<0>, B1<0>; stage B0 <- kt+2
        lda_f<0>(A1, wr, lm, lk, aF);
        ldb_f<0>(B1, wc, lm, lk, bF);
        if (s2) SB(0, kt + 2);
        LGKM8();
        BAR(); LGKM0();
        mma16<0, 0>(aF, bF, acc);
        BAR();
        // ph6 : (0,1)  reads B1<1>
        ldb_f<1>(B1, wc, lm, lk, bF);
        BAR(); LGKM0();
        mma16<0, 1>(aF, bF, acc);
        BAR();
        // ph7 : (1,1)  reads A1<1>  (A1 free after)
        lda_f<1>(A1, wr, lm, lk, aF);
        BAR(); LGKM0();
        mma16<1, 1>(aF, bF, acc);
        BAR();
        // ph8 : (1,0)  re-reads B1<0> (B1 free after); stage A1 <- kt+3
        ldb_f<0>(B1, wc, lm, lk, bF);
        if (s2) SA(1, kt + 3);
        BAR(); LGKM0();
        mma16<1, 0>(aF, bF, acc);
        if (s2) { VM4(); }                   // A0,B0 (kt+2) complete before ph1
        BAR();
    }
#undef SA
#undef SB

    // ---- epilogue: exp2(acc*C1 - C1), 16-lane row reduce, atomicAdd ----
    // C/D layout: col = lane&15, row = (lane>>4)*4 + reg  [m89/m91]
    float* rowpart = (float*)lds;    // A0 region, dead
    constexpr float C1 = 14.4269504088896340736f;   // 10 * log2(e)

#pragma unroll
    for (int mi = 0; mi < 8; mi++) {
#pragma unroll
        for (int r = 0; r < 4; r++) {
            float s = 0.f;
#pragma unroll
            for (int n = 0; n < 4; n++)
                s += exp2f(fmaf(acc[mi][n][r], C1, -C1));
#pragma unroll
            for (int msk = 1; msk < 16; msk <<= 1) s += __shfl_xor(s, msk);
            if (lm == 0)
                rowpart[(wr * 128 + mi * 16 + lk * 4 + r) * 4 + wc] = s;
        }
    }
    __syncthreads();
    if (t < 256) {
        const float v = rowpart[t * 4 + 0] + rowpart[t * 4 + 1] +
                        rowpart[t * 4 + 2] + rowpart[t * 4 + 3];
        atomicAdd(&S[tileM * 256 + t], v);
    }
}

// ---------------------------------------------------------------------------
// Kernel 3: loss = mean_i( 10 + log(S_i) - diag_i )
// ---------------------------------------------------------------------------
__global__ __launch_bounds__(1024) void loss_kernel(
    const float* __restrict__ S, const float* __restrict__ diag,
    float* __restrict__ out)
{
    const int t = threadIdx.x;
    float acc = 0.f;
    for (int i = t; i < N_ROWS; i += 1024)
        acc += 10.0f + logf(S[i]) - diag[i];
#pragma unroll
    for (int m = 1; m < 64; m <<= 1) acc += __shfl_xor(acc, m);
    __shared__ float red[16];
    if ((t & 63) == 0) red[t >> 6] = acc;
    __syncthreads();
    if (t == 0) {
        float s = 0.f;
        for (int i = 0; i < 16; i++) s += red[i];
        out[0] = s * (1.0f / N_ROWS);
    }
}

// ---------------------------------------------------------------------------
extern "C" void kernel_launch(void* const* d_in, const int* in_sizes, int n_in,
                              void* d_out, int out_size, void* d_ws, size_t ws_size,
                              hipStream_t stream)
{
    const float* A = (const float*)d_in[0];   // image_emb  [8192,1024] f32
    const float* B = (const float*)d_in[1];   // sensor_emb [8192,1024] f32
    float* out = (float*)d_out;

    short* a_bf = (short*)d_ws;
    short* b_bf = a_bf + (size_t)N_ROWS * DIM;
    float* S    = (float*)(b_bf + (size_t)N_ROWS * DIM);
    float* diag = S + N_ROWS;

    normalize_kernel<<<N_ROWS, 256, 0, stream>>>(A, B, a_bf, b_bf, diag, S);
    gemm_lse_kernel<<<1024, 512, 131072, stream>>>(a_bf, b_bf, S);
    loss_kernel<<<1, 1024, 0, stream>>>(S, diag, out);
}

// Round 5
// 222.565 us; speedup vs baseline: 1.2833x; 1.2134x over previous
//
#include <hip/hip_runtime.h>
#include <hip/hip_bf16.h>
#include <cstdint>

#define N_ROWS 8192
#define DIM    1024

typedef __attribute__((ext_vector_type(4))) float  f32x4;
typedef __attribute__((ext_vector_type(8))) __bf16 bf16x8;

__device__ __forceinline__ unsigned short f2bf(float x) {
    unsigned int u = __float_as_uint(x);
    u += 0x7fffu + ((u >> 16) & 1u);   // round-to-nearest-even
    return (unsigned short)(u >> 16);
}

// ---------------------------------------------------------------------------
// Kernel 1: per-row L2 normalize (fp32 -> bf16), fp32 diagonal logit, zero S.
// One WAVE per row: 64 lanes x float4 = 1024 elems; pure shfl reduce,
// no LDS, no __syncthreads. 2048 blocks x 256 thr (4 rows/block).
// ---------------------------------------------------------------------------
__global__ __launch_bounds__(256) void normalize_kernel(
    const float* __restrict__ A, const float* __restrict__ B,
    short* __restrict__ Abf, short* __restrict__ Bbf,
    float* __restrict__ diag, float* __restrict__ S)
{
    const int wave = threadIdx.x >> 6;
    const int lane = threadIdx.x & 63;
    const int row  = blockIdx.x * 4 + wave;

    const float4 a = reinterpret_cast<const float4*>(A)[row * (DIM / 4) + lane];
    const float4 b = reinterpret_cast<const float4*>(B)[row * (DIM / 4) + lane];

    float ssA = a.x * a.x + a.y * a.y + a.z * a.z + a.w * a.w;
    float ssB = b.x * b.x + b.y * b.y + b.z * b.z + b.w * b.w;
#pragma unroll
    for (int m = 1; m < 64; m <<= 1) {
        ssA += __shfl_xor(ssA, m);
        ssB += __shfl_xor(ssB, m);
    }
    const float ia = 1.0f / fmaxf(sqrtf(ssA), 1e-8f);
    const float ib = 1.0f / fmaxf(sqrtf(ssB), 1e-8f);

    const float anx = a.x * ia, any = a.y * ia, anz = a.z * ia, anw = a.w * ia;
    const float bnx = b.x * ib, bny = b.y * ib, bnz = b.z * ib, bnw = b.w * ib;

    ushort4 pa, pb;
    pa.x = f2bf(anx); pa.y = f2bf(any); pa.z = f2bf(anz); pa.w = f2bf(anw);
    pb.x = f2bf(bnx); pb.y = f2bf(bny); pb.z = f2bf(bnz); pb.w = f2bf(bnw);
    reinterpret_cast<ushort4*>(Abf)[row * (DIM / 4) + lane] = pa;
    reinterpret_cast<ushort4*>(Bbf)[row * (DIM / 4) + lane] = pb;

    float d = anx * bnx + any * bny + anz * bnz + anw * bnw;
#pragma unroll
    for (int m = 1; m < 64; m <<= 1) d += __shfl_xor(d, m);
    if (lane == 0) {
        diag[row] = d * 10.0f;   // /T
        S[row] = 0.0f;           // ws is poisoned 0xAA each launch
    }
}

// ---------------------------------------------------------------------------
// Kernel 2: PERSISTENT 256x256x(BK=64) 8-phase bf16 GEMM (A·B^T) +
// exp(logit-10) row-sum epilogue per segment.
//   256 blocks (1/CU), each: tileM fixed, 4 tileN segments, flattened
//   64-K-tile loop with CONTINUOUS staging across segment boundaries
//   (effective K = 4096 -> m201 amortization regime).
//   Inner 8-phase schedule, swizzle, and vmcnt ledger identical to the
//   round-3/4 verified structure:
//     swz byte^((row&7)<<4) both sides; stages B1@ph1, A0@ph4, B0@ph5,
//     A1@ph8 (full tile = 4 loads/thread); VM4 at ph4/ph8; raw s_barrier;
//     setprio(1) around MFMA clusters.
//   Segment epilogue: rowpart scratch in B1 region (dead between its ph8
//   read and next ph1 stage); LGKM0+BAR sync only (no vmcnt drain).
// ---------------------------------------------------------------------------
#define BAR()   __builtin_amdgcn_s_barrier()
#define LGKM0() asm volatile("s_waitcnt lgkmcnt(0)" ::: "memory")
#define LGKM8() asm volatile("s_waitcnt lgkmcnt(8)" ::: "memory")
#define VM4()   asm volatile("s_waitcnt vmcnt(4)" ::: "memory")
#define VM0()   asm volatile("s_waitcnt vmcnt(0)" ::: "memory")

__device__ __forceinline__ void stage_half(const short* __restrict__ gsrc,
                                           short* ldst, int t)
{
#pragma unroll
    for (int i = 0; i < 2; i++) {
        const int d    = (i * 512 + t) * 16;                 // dest byte 0..16383
        const int row  = d >> 7;                             // 0..127
        const int colb = (d & 127) ^ ((row & 7) << 4);       // swz bits4-6
        __builtin_amdgcn_global_load_lds(
            (const __attribute__((address_space(1))) void*)((const char*)gsrc + (size_t)row * (DIM * 2) + colb),
            (__attribute__((address_space(3))) void*)((char*)ldst + d), 16, 0, 0);
    }
}

template<int MH>
__device__ __forceinline__ void lda_f(const char* base, int wr, int lm, int lk,
                                      bf16x8 (&aF)[4][2])
{
#pragma unroll
    for (int m = 0; m < 4; m++)
#pragma unroll
        for (int ks = 0; ks < 2; ks++) {
            const int row = wr * 128 + MH * 64 + m * 16 + lm;
            const int b   = (row * 128 + ks * 64 + lk * 16) ^ ((row & 7) << 4);
            aF[m][ks] = *reinterpret_cast<const bf16x8*>(base + b);
        }
}

template<int NH>
__device__ __forceinline__ void ldb_f(const char* base, int wc, int lm, int lk,
                                      bf16x8 (&bF)[2][2])
{
#pragma unroll
    for (int n = 0; n < 2; n++)
#pragma unroll
        for (int ks = 0; ks < 2; ks++) {
            const int row = wc * 64 + NH * 32 + n * 16 + lm;
            const int b   = (row * 128 + ks * 64 + lk * 16) ^ ((row & 7) << 4);
            bF[n][ks] = *reinterpret_cast<const bf16x8*>(base + b);
        }
}

template<int MH, int NP>
__device__ __forceinline__ void mma16(const bf16x8 (&aF)[4][2],
                                      const bf16x8 (&bF)[2][2],
                                      f32x4 (&acc)[8][4])
{
    __builtin_amdgcn_s_setprio(1);
#pragma unroll
    for (int m = 0; m < 4; m++)
#pragma unroll
        for (int n = 0; n < 2; n++)
#pragma unroll
            for (int ks = 0; ks < 2; ks++)
                acc[MH * 4 + m][NP * 2 + n] = __builtin_amdgcn_mfma_f32_16x16x32_bf16(
                    aF[m][ks], bF[n][ks], acc[MH * 4 + m][NP * 2 + n], 0, 0, 0);
    __builtin_amdgcn_s_setprio(0);
}

__global__ __launch_bounds__(512, 2) void gemm_lse_kernel(
    const short* __restrict__ Abf, const short* __restrict__ Bbf,
    float* __restrict__ S)
{
    extern __shared__ short lds[];   // 131072 B: A0|A1|B0|B1, each [256][64] bf16

    const int t    = threadIdx.x;    // 0..511
    const int lane = t & 63;
    const int wave = t >> 6;         // 0..7
    const int wr   = wave >> 2;      // 0..1
    const int wc   = wave & 3;       // 0..3
    const int lm   = lane & 15;
    const int lk   = lane >> 4;

    // persistent mapping: 256 blocks, 1/CU. tileM fixed per block; tileN
    // walks 4 segments. Per-XCD concurrent: 4 tileM x 8 tileN.
    const int xcd   = blockIdx.x & 7;
    const int cu    = blockIdx.x >> 3;           // 0..31
    const int tileM = xcd * 4 + (cu & 3);        // 0..31, fixed
    const int nBase = cu >> 2;                   // 0..7

    const short* Ag = Abf + (size_t)tileM * 256 * DIM;

    char* const A0 = (char*)lds;
    char* const A1 = (char*)lds + 32768;
    char* const B0 = (char*)lds + 65536;
    char* const B1 = (char*)lds + 98304;

    // B base for flattened k-tile index gg (segment = gg>>4)
#define BPTR(gg) (Bbf + (size_t)((nBase + 8 * ((gg) >> 4)) & 31) * 256 * DIM)
    // full-tile stages (4 loads/thread), k-offset = (gg&15)*64
#define SA(buf, gg) { stage_half(Ag + ((gg) & 15) * 64,                 lds + (buf) * 16384,        t); \
                      stage_half(Ag + 128 * DIM + ((gg) & 15) * 64,     lds + (buf) * 16384 + 8192, t); }
#define SB(buf, gg) { const short* Bg_ = BPTR(gg); \
                      stage_half(Bg_ + ((gg) & 15) * 64,                lds + 32768 + (buf) * 16384,        t); \
                      stage_half(Bg_ + 128 * DIM + ((gg) & 15) * 64,    lds + 32768 + (buf) * 16384 + 8192, t); }

    // ---- prologue: A0,B0 <- g0 (8 loads), A1 <- g1 (4). VM4 -> g0 done.
    SA(0, 0); SB(0, 0);
    SA(1, 1);
    VM4();
    BAR();

    f32x4 acc[8][4];
#pragma unroll
    for (int m = 0; m < 8; m++)
#pragma unroll
        for (int n = 0; n < 4; n++) acc[m][n] = (f32x4){0.f, 0.f, 0.f, 0.f};

    bf16x8 aF[4][2], bF[2][2];
    constexpr float C1 = 14.4269504088896340736f;   // 10 * log2(e)

    for (int gi = 0; gi < 32; ++gi) {
        const int g = 2 * gi;            // even flattened k-tile (buf0); g+1 -> buf1

        // ph1 : (0,0)  reads A0<0>, B0<0>; stage B1 <- g+1
        lda_f<0>(A0, wr, lm, lk, aF);
        ldb_f<0>(B0, wc, lm, lk, bF);
        SB(1, g + 1);
        LGKM8();
        BAR(); LGKM0();
        mma16<0, 0>(aF, bF, acc);
        BAR();
        // ph2 : (0,1)  reads B0<1>
        ldb_f<1>(B0, wc, lm, lk, bF);
        BAR(); LGKM0();
        mma16<0, 1>(aF, bF, acc);
        BAR();
        // ph3 : (1,1)  reads A0<1>  (A0 free after)
        lda_f<1>(A0, wr, lm, lk, aF);
        BAR(); LGKM0();
        mma16<1, 1>(aF, bF, acc);
        BAR();
        // ph4 : (1,0)  re-reads B0<0> (B0 free after); stage A0 <- g+2
        ldb_f<0>(B0, wc, lm, lk, bF);
        if (g + 2 < 64) SA(0, g + 2);
        BAR(); LGKM0();
        mma16<1, 0>(aF, bF, acc);
        if (g + 2 < 64) { VM4(); } else { VM0(); }   // g+1 tiles complete
        BAR();

        // ph5 : (0,0)  reads A1<0>, B1<0>; stage B0 <- g+2
        lda_f<0>(A1, wr, lm, lk, aF);
        ldb_f<0>(B1, wc, lm, lk, bF);
        if (g + 2 < 64) SB(0, g + 2);
        LGKM8();
        BAR(); LGKM0();
        mma16<0, 0>(aF, bF, acc);
        BAR();
        // ph6 : (0,1)  reads B1<1>
        ldb_f<1>(B1, wc, lm, lk, bF);
        BAR(); LGKM0();
        mma16<0, 1>(aF, bF, acc);
        BAR();
        // ph7 : (1,1)  reads A1<1>  (A1 free after)
        lda_f<1>(A1, wr, lm, lk, aF);
        BAR(); LGKM0();
        mma16<1, 1>(aF, bF, acc);
        BAR();
        // ph8 : (1,0)  re-reads B1<0> (B1 free after); stage A1 <- g+3
        ldb_f<0>(B1, wc, lm, lk, bF);
        if (g + 3 < 64) SA(1, g + 3);
        BAR(); LGKM0();
        mma16<1, 0>(aF, bF, acc);
        if (g + 3 < 64) { VM4(); }                   // g+2 A0,B0 complete
        BAR();

        // ---- segment epilogue (after local kt=15, i.e. g&15==14) ----
        // B1 region is dead: last read was ph8; next write is next ph1's SB.
        if ((g & 15) == 14) {
            float* rowpart = (float*)((char*)lds + 98304);   // B1 region
#pragma unroll
            for (int mi = 0; mi < 8; mi++) {
#pragma unroll
                for (int r = 0; r < 4; r++) {
                    float s = 0.f;
#pragma unroll
                    for (int n = 0; n < 4; n++)
                        s += exp2f(fmaf(acc[mi][n][r], C1, -C1));
#pragma unroll
                    for (int msk = 1; msk < 16; msk <<= 1) s += __shfl_xor(s, msk);
                    if (lm == 0)
                        rowpart[(wr * 128 + mi * 16 + lk * 4 + r) * 4 + wc] = s;
                }
            }
            LGKM0();    // my rowpart writes done
            BAR();      // all writes visible
            if (t < 256) {
                const float v = rowpart[t * 4 + 0] + rowpart[t * 4 + 1] +
                                rowpart[t * 4 + 2] + rowpart[t * 4 + 3];
                atomicAdd(&S[tileM * 256 + t], v);   // reads retired before use
            }
            BAR();      // rowpart reads consumed before next ph1 stages B1
            // reset accumulator for next segment
#pragma unroll
            for (int m = 0; m < 8; m++)
#pragma unroll
                for (int n = 0; n < 4; n++) acc[m][n] = (f32x4){0.f, 0.f, 0.f, 0.f};
        }
    }
#undef SA
#undef SB
#undef BPTR
}

// ---------------------------------------------------------------------------
// Kernel 3: loss = mean_i( 10 + log(S_i) - diag_i )
// ---------------------------------------------------------------------------
__global__ __launch_bounds__(1024) void loss_kernel(
    const float* __restrict__ S, const float* __restrict__ diag,
    float* __restrict__ out)
{
    const int t = threadIdx.x;
    float acc = 0.f;
#pragma unroll
    for (int i = 0; i < 2; i++) {
        const int idx = i * 1024 + t;
        const float4 s4 = reinterpret_cast<const float4*>(S)[idx];
        const float4 d4 = reinterpret_cast<const float4*>(diag)[idx];
        acc += (10.0f + logf(s4.x) - d4.x) + (10.0f + logf(s4.y) - d4.y)
             + (10.0f + logf(s4.z) - d4.z) + (10.0f + logf(s4.w) - d4.w);
    }
#pragma unroll
    for (int m = 1; m < 64; m <<= 1) acc += __shfl_xor(acc, m);
    __shared__ float red[16];
    if ((t & 63) == 0) red[t >> 6] = acc;
    __syncthreads();
    if (t == 0) {
        float s = 0.f;
        for (int i = 0; i < 16; i++) s += red[i];
        out[0] = s * (1.0f / N_ROWS);
    }
}

// ---------------------------------------------------------------------------
extern "C" void kernel_launch(void* const* d_in, const int* in_sizes, int n_in,
                              void* d_out, int out_size, void* d_ws, size_t ws_size,
                              hipStream_t stream)
{
    const float* A = (const float*)d_in[0];   // image_emb  [8192,1024] f32
    const float* B = (const float*)d_in[1];   // sensor_emb [8192,1024] f32
    float* out = (float*)d_out;

    short* a_bf = (short*)d_ws;
    short* b_bf = a_bf + (size_t)N_ROWS * DIM;
    float* S    = (float*)(b_bf + (size_t)N_ROWS * DIM);
    float* diag = S + N_ROWS;

    normalize_kernel<<<N_ROWS / 4, 256, 0, stream>>>(A, B, a_bf, b_bf, diag, S);
    gemm_lse_kernel<<<256, 512, 131072, stream>>>(a_bf, b_bf, S);
    loss_kernel<<<1, 1024, 0, stream>>>(S, diag, out);
}